// Round 4
// baseline (294.439 us; speedup 1.0000x reference)
//
#include <hip/hip_runtime.h>
#include <math.h>

#define B_ 8
#define T_ 4096
#define M_ 1024
#define TT 32          // rows per block tile; grid = B_ * (T_/TT) = 1024 blocks
#define CH 8           // chunk rows: 8 independent loads in flight per wave (MLP=8)
#define EPSF 1e-6f

// Native clang vector type: __builtin_nontemporal_store rejects HIP's
// float4 class (HIP_vector_type), but accepts ext_vector_type.
typedef float fvec4 __attribute__((ext_vector_type(4)));

// 16-tap causal bump convolution along T + per-channel softplus gate.
// out[b,t,m] = gate[m] * (1/S_t) * sum_{d=0}^{15} w[d] * x[b,t-d,m]
//
// Round-3 post-mortem: the MLP=8 register double-buffer compiled to VGPR=84 —
// too small to hold ring(64) + prefetch(32) + state, proving the compiler SANK
// the prefetch loads toward their uses (live-range shrinking), serializing the
// batch back to ~4-deep. BW stayed pinned at 2.8 TB/s, VALUBusy 13%.
// Fix: __builtin_amdgcn_sched_barrier(0) after each 8-load cluster pins the
// loads above the compute (nothing may cross the fence), and
// __launch_bounds__(256,4) caps VGPR at 128 so the now-live buffer still
// permits 4 waves/SIMD = 16 waves/CU (grid provides exactly 4 blocks/CU).
// Target in-flight: 8 KB/wave x 16 waves/CU = 128 KB/CU >> ~10-30 KB needed
// by Little's law at loaded latency.
__global__ __launch_bounds__(256, 4) void bump_conv_kernel(
    const float* __restrict__ x,
    const float* __restrict__ gate_raw,
    float* __restrict__ out) {
  const int tiles = T_ / TT;               // 128
  // XCD-aware bijective swizzle (nwg = 1024, 1024 % 8 == 0): each XCD owns a
  // contiguous run of tiles so co-resident neighbors share their 15-row halo
  // in that XCD's L2.
  const int nwg = B_ * tiles;              // 1024
  const int cpx = nwg / 8;                 // 128
  const int lin = (blockIdx.x % 8) * cpx + blockIdx.x / 8;
  const int tile = lin % tiles;
  const int b    = lin / tiles;
  const int t0   = tile * TT;              // multiple of 16 -> ring slot = t & 15
  const int m    = threadIdx.x * 4;        // 256 threads * float4 = M_

  // --- taps (compile-time constants after constant folding) ---
  float w[16];
  float S = 0.0f;
#pragma unroll
  for (int d = 0; d < 16; ++d) {
    float u = fminf((float)d * (1.0f / 15.0f), 1.0f - EPSF);
    float den = 1.0f - u * u + EPSF;
    w[d] = expf(1.0f - 1.0f / den);        // d=15 -> expf(-3.3e5) == 0.0f
    S += w[d];
  }
  const float rsS = 1.0f / fmaxf(S, EPSF);

  // --- per-channel gate: softplus(gate_raw) ---
  const fvec4 graw = *(const fvec4*)(gate_raw + m);
  fvec4 g;
  g.x = fmaxf(graw.x, 0.0f) + log1pf(expf(-fabsf(graw.x)));
  g.y = fmaxf(graw.y, 0.0f) + log1pf(expf(-fabsf(graw.y)));
  g.z = fmaxf(graw.z, 0.0f) + log1pf(expf(-fabsf(graw.z)));
  g.w = fmaxf(graw.w, 0.0f) + log1pf(expf(-fabsf(graw.w)));

  const float* xb = x   + (size_t)b * T_ * M_ + m;
  float*       ob = out + (size_t)b * T_ * M_ + m;

  // --- ring buffer: slot for row t is (t & 15) ---
  fvec4 r[16];
  r[0] = (fvec4)(0.f);
#pragma unroll
  for (int k = 1; k <= 15; ++k) {          // halo rows t0-15 .. t0-1 -> slots 1..15
    const int t = t0 - 16 + k;
    r[k] = (t >= 0) ? *(const fvec4*)(xb + (size_t)t * M_)
                    : (fvec4)(0.f);
  }

  // --- chunk double-buffer in registers; all indices static after unroll ---
  fvec4 pb[2][CH];
#pragma unroll
  for (int s = 0; s < CH; ++s)             // chunk 0: 8 independent loads
    pb[0][s] = *(const fvec4*)(xb + (size_t)(t0 + s) * M_);
  __builtin_amdgcn_sched_barrier(0);       // pin prologue loads above loop body

#pragma unroll
  for (int c = 0; c < TT / CH; ++c) {      // 4 chunks, fully unrolled
    const int cur = c & 1;
    const int nxb = cur ^ 1;
    const int tc  = t0 + c * CH;

    if (c + 1 < TT / CH) {                 // issue next chunk's 8 loads; fence
#pragma unroll                             // forbids sinking them into compute
      for (int s = 0; s < CH; ++s)
        pb[nxb][s] = *(const fvec4*)(xb + (size_t)(tc + CH + s) * M_);
      __builtin_amdgcn_sched_barrier(0);
    }

#pragma unroll
    for (int s = 0; s < CH; ++s) {
      const int t = tc + s;
      r[(c * CH + s) & 15] = pb[cur][s];   // slot (t & 15); static index

      float ax = 0.f, ay = 0.f, az = 0.f, aw = 0.f;
#pragma unroll
      for (int d = 0; d < 16; ++d) {
        const fvec4 v = r[((c * CH + s) - d + 16) & 15];  // static index
        const float wd = w[d];
        ax = fmaf(wd, v.x, ax);
        ay = fmaf(wd, v.y, ay);
        az = fmaf(wd, v.z, az);
        aw = fmaf(wd, v.w, aw);
      }

      float sc = rsS;
      if (t < 15) {                        // wave-uniform; only tile 0
        float p = 0.0f;
#pragma unroll
        for (int d = 0; d < 16; ++d) p += (d <= t) ? w[d] : 0.0f;
        sc = 1.0f / fmaxf(p, EPSF);
      }

      fvec4 o;
      o.x = ax * sc * g.x;
      o.y = ay * sc * g.y;
      o.z = az * sc * g.z;
      o.w = aw * sc * g.w;
      // Output is write-once/never-read: nontemporal store keeps it from
      // evicting x out of the Infinity Cache (x is L3-resident across
      // dispatches: FETCH 95 MB < 134 MB unique reads).
      __builtin_nontemporal_store(o, (fvec4*)(ob + (size_t)t * M_));
    }
  }
}

extern "C" void kernel_launch(void* const* d_in, const int* in_sizes, int n_in,
                              void* d_out, int out_size, void* d_ws, size_t ws_size,
                              hipStream_t stream) {
  const float* x         = (const float*)d_in[0];
  // d_in[1] = mask (T,T): redundant (taps already causal) -- intentionally unread.
  const float* gate_raw  = (const float*)d_in[2];
  float*       out       = (float*)d_out;

  dim3 grid(B_ * (T_ / TT));   // 1024 blocks
  dim3 block(256);
  bump_conv_kernel<<<grid, block, 0, stream>>>(x, gate_raw, out);
}

// Round 5
// 263.885 us; speedup vs baseline: 1.1158x; 1.1158x over previous
//
#include <hip/hip_runtime.h>
#include <math.h>

#define B_ 8
#define T_ 4096
#define M_ 1024
#define CT 8           // outputs per thread along t; 23 = CT+15 independent loads
#define EPSF 1e-6f

// Native clang vector type: __builtin_nontemporal_store rejects HIP's
// float4 class (HIP_vector_type), but accepts ext_vector_type.
typedef float fvec4 __attribute__((ext_vector_type(4)));

// 16-tap causal bump convolution along T + per-channel softplus gate.
// out[b,t,m] = gate[m] * (1/S_t) * sum_{d=0}^{15} w[d] * x[b,t-d,m]
//
// Round-4 post-mortem: sched_barrier(0) pinning caused scratch spills
// (WRITE_SIZE 131->197 MB, FETCH +38 MB, VGPR 64) — reverted. Across 5 configs
// (2..16 waves/CU, prefetch depth 1..8) HBM BW sat pinned at 2.4-2.9 TB/s:
// the serial per-wave row-walk (47-iteration dependent loop of
// wait->FMA->store) never behaves like the 6.3 TB/s copy kernel.
//
// This version removes ALL serial structure: one block = one (b, 8-row
// t-chunk); each thread computes 8 outputs from 23 fully independent loads
// (rows t0-15..t0+7), fully unrolled, then exits. 4096 short-lived blocks.
// Read amplification 23/8 = 2.9x is absorbed by L1 (64 lanes share the same
// 23 rows) and L2 (adjacent chunks share 15 rows; XCD swizzle keeps
// consecutive chunks on one XCD): ~390 MB logical / 34.5 TB/s L2 ~= 11 us,
// not a limit. No ring, no cross-iteration dependence -> compiler hoists all
// 23 loads as a register tile (MLP=23/thread at issue).
__global__ __launch_bounds__(256) void bump_conv_kernel(
    const float* __restrict__ x,
    const float* __restrict__ gate_raw,
    float* __restrict__ out) {
  const int chunks = T_ / CT;              // 512 chunks per batch
  const int nwg = B_ * chunks;             // 4096 blocks
  const int cpx = nwg / 8;                 // 512 per XCD
  const int lin = ((int)blockIdx.x % 8) * cpx + (int)blockIdx.x / 8;
  const int b     = lin / chunks;
  const int chunk = lin % chunks;
  const int t0    = chunk * CT;
  const int m     = threadIdx.x * 4;       // 256 threads * float4 = M_

  // --- taps (literal args; LLVM constant-folds these at -O3) ---
  float w[16];
  float S = 0.0f;
#pragma unroll
  for (int d = 0; d < 16; ++d) {
    float u = fminf((float)d * (1.0f / 15.0f), 1.0f - EPSF);
    float den = 1.0f - u * u + EPSF;
    w[d] = expf(1.0f - 1.0f / den);        // d=15 -> expf(-3.3e5) == 0.0f
    S += w[d];
  }
  const float rsS = 1.0f / fmaxf(S, EPSF);

  // --- per-channel gate: softplus(gate_raw) ---
  const fvec4 graw = *(const fvec4*)(gate_raw + m);
  fvec4 g;
  g.x = fmaxf(graw.x, 0.0f) + log1pf(expf(-fabsf(graw.x)));
  g.y = fmaxf(graw.y, 0.0f) + log1pf(expf(-fabsf(graw.y)));
  g.z = fmaxf(graw.z, 0.0f) + log1pf(expf(-fabsf(graw.z)));
  g.w = fmaxf(graw.w, 0.0f) + log1pf(expf(-fabsf(graw.w)));

  const float* xb = x   + (size_t)b * T_ * M_ + m;
  float*       ob = out + (size_t)b * T_ * M_ + m;

  // --- 23 independent row loads: rows t0-15 .. t0+7, all static indices ---
  fvec4 v[CT + 15];
#pragma unroll
  for (int j = 0; j < CT + 15; ++j) {
    const int t = t0 - 15 + j;
    v[j] = (t >= 0) ? *(const fvec4*)(xb + (size_t)t * M_)
                    : (fvec4)(0.f);
  }

  // --- 8 outputs; output t=t0+s uses v[s .. s+15] (j = s+15-d) ---
#pragma unroll
  for (int s = 0; s < CT; ++s) {
    const int t = t0 + s;

    float ax = 0.f, ay = 0.f, az = 0.f, aw = 0.f;
#pragma unroll
    for (int d = 0; d < 16; ++d) {
      const fvec4 vv = v[s + 15 - d];      // static index
      const float wd = w[d];
      ax = fmaf(wd, vv.x, ax);
      ay = fmaf(wd, vv.y, ay);
      az = fmaf(wd, vv.z, az);
      aw = fmaf(wd, vv.w, aw);
    }

    float sc = rsS;
    if (t < 15) {                          // only chunks 0,1 of each batch
      float p = 0.0f;
#pragma unroll
      for (int d = 0; d < 16; ++d) p += (d <= t) ? w[d] : 0.0f;
      sc = 1.0f / fmaxf(p, EPSF);
    }

    fvec4 o;
    o.x = ax * sc * g.x;
    o.y = ay * sc * g.y;
    o.z = az * sc * g.z;
    o.w = aw * sc * g.w;
    // Output is write-once/never-read: nontemporal store keeps it from
    // evicting x out of the Infinity Cache.
    __builtin_nontemporal_store(o, (fvec4*)(ob + (size_t)t * M_));
  }
}

extern "C" void kernel_launch(void* const* d_in, const int* in_sizes, int n_in,
                              void* d_out, int out_size, void* d_ws, size_t ws_size,
                              hipStream_t stream) {
  const float* x         = (const float*)d_in[0];
  // d_in[1] = mask (T,T): redundant (taps already causal) -- intentionally unread.
  const float* gate_raw  = (const float*)d_in[2];
  float*       out       = (float*)d_out;

  dim3 grid(B_ * (T_ / CT));   // 4096 blocks
  dim3 block(256);
  bump_conv_kernel<<<grid, block, 0, stream>>>(x, gate_raw, out);
}

// Round 6
// 263.447 us; speedup vs baseline: 1.1176x; 1.0017x over previous
//
#include <hip/hip_runtime.h>
#include <math.h>

#define B_ 8
#define T_ 4096
#define M_ 1024
#define CT 8           // outputs per thread along t; 23 = CT+15 independent loads
#define EPSF 1e-6f

// Native clang vector type: __builtin_nontemporal_store rejects HIP's
// float4 class (HIP_vector_type), but accepts ext_vector_type.
typedef float fvec4 __attribute__((ext_vector_type(4)));

// 16-tap causal bump convolution along T + per-channel softplus gate.
// out[b,t,m] = gate[m] * (1/S_t) * sum_{d=0}^{15} w[d] * x[b,t-d,m]
//
// Round-5 post-mortem: VGPR_Count=68 — 23 live float4 loads need >=92 VGPRs,
// so the compiler sank the loads into load->use chains AGAIN (same root cause
// as rounds 2-4). Wave-lifetime budget confirms MLP~1: lifetime ~28K cy, VALU
// ~3.5K, stall ~24K = 23 loads x ~1000 cy serial. Plain launch_bounds(256)
// lets the scheduler target ~8 waves/SIMD (~68 VGPR) and its pressure
// heuristic kills the register tile.
//
// Fix (single variable vs round 5): __launch_bounds__(256, 2) raises the VGPR
// ceiling to 256 so the natural source order (23 loads, then compute)
// survives scheduling. 2 waves/SIMD x 23 KB outstanding = >100 KB in flight
// per CU vs ~10-30 KB needed by Little's law at loaded latency. VALU floor at
// 2 waves/SIMD is ~24 us < ~45 us memory roofline, so the occupancy cap is
// affordable. NO sched_barrier (round 4 showed fence + tight VGPR cap =
// scratch spills, WRITE_SIZE 131->197 MB).
__global__ __launch_bounds__(256, 2) void bump_conv_kernel(
    const float* __restrict__ x,
    const float* __restrict__ gate_raw,
    float* __restrict__ out) {
  const int chunks = T_ / CT;              // 512 chunks per batch
  const int nwg = B_ * chunks;             // 4096 blocks
  const int cpx = nwg / 8;                 // 512 per XCD
  const int lin = ((int)blockIdx.x % 8) * cpx + (int)blockIdx.x / 8;
  const int b     = lin / chunks;
  const int chunk = lin % chunks;
  const int t0    = chunk * CT;
  const int m     = threadIdx.x * 4;       // 256 threads * float4 = M_

  // --- taps (llvm.exp.f32 on constants folds at -O3) ---
  float w[16];
  float S = 0.0f;
#pragma unroll
  for (int d = 0; d < 16; ++d) {
    float u = fminf((float)d * (1.0f / 15.0f), 1.0f - EPSF);
    float den = 1.0f - u * u + EPSF;
    w[d] = expf(1.0f - 1.0f / den);        // d=15 -> expf(-3.3e5) == 0.0f
    S += w[d];
  }
  const float rsS = 1.0f / fmaxf(S, EPSF);

  // --- per-channel gate: softplus(gate_raw) ---
  const fvec4 graw = *(const fvec4*)(gate_raw + m);
  fvec4 g;
  g.x = fmaxf(graw.x, 0.0f) + log1pf(expf(-fabsf(graw.x)));
  g.y = fmaxf(graw.y, 0.0f) + log1pf(expf(-fabsf(graw.y)));
  g.z = fmaxf(graw.z, 0.0f) + log1pf(expf(-fabsf(graw.z)));
  g.w = fmaxf(graw.w, 0.0f) + log1pf(expf(-fabsf(graw.w)));

  const float* xb = x   + (size_t)b * T_ * M_ + m;
  float*       ob = out + (size_t)b * T_ * M_ + m;

  // --- 23 independent row loads: rows t0-15 .. t0+7, all static indices ---
  fvec4 v[CT + 15];
#pragma unroll
  for (int j = 0; j < CT + 15; ++j) {
    const int t = t0 - 15 + j;
    v[j] = (t >= 0) ? *(const fvec4*)(xb + (size_t)t * M_)
                    : (fvec4)(0.f);
  }

  // --- 8 outputs; output t=t0+s uses v[s .. s+15] (j = s+15-d) ---
#pragma unroll
  for (int s = 0; s < CT; ++s) {
    const int t = t0 + s;

    float ax = 0.f, ay = 0.f, az = 0.f, aw = 0.f;
#pragma unroll
    for (int d = 0; d < 16; ++d) {
      const fvec4 vv = v[s + 15 - d];      // static index
      const float wd = w[d];
      ax = fmaf(wd, vv.x, ax);
      ay = fmaf(wd, vv.y, ay);
      az = fmaf(wd, vv.z, az);
      aw = fmaf(wd, vv.w, aw);
    }

    float sc = rsS;
    if (t < 15) {                          // only chunks 0,1 of each batch
      float p = 0.0f;
#pragma unroll
      for (int d = 0; d < 16; ++d) p += (d <= t) ? w[d] : 0.0f;
      sc = 1.0f / fmaxf(p, EPSF);
    }

    fvec4 o;
    o.x = ax * sc * g.x;
    o.y = ay * sc * g.y;
    o.z = az * sc * g.z;
    o.w = aw * sc * g.w;
    // Output is write-once/never-read: nontemporal store keeps it from
    // evicting x out of the Infinity Cache (FETCH 65 MB < 134 MB unique
    // confirms x is largely L3-resident).
    __builtin_nontemporal_store(o, (fvec4*)(ob + (size_t)t * M_));
  }
}

extern "C" void kernel_launch(void* const* d_in, const int* in_sizes, int n_in,
                              void* d_out, int out_size, void* d_ws, size_t ws_size,
                              hipStream_t stream) {
  const float* x         = (const float*)d_in[0];
  // d_in[1] = mask (T,T): redundant (taps already causal) -- intentionally unread.
  const float* gate_raw  = (const float*)d_in[2];
  float*       out       = (float*)d_out;

  dim3 grid(B_ * (T_ / CT));   // 4096 blocks
  dim3 block(256);
  bump_conv_kernel<<<grid, block, 0, stream>>>(x, gate_raw, out);
}

// Round 7
// 263.117 us; speedup vs baseline: 1.1190x; 1.0013x over previous
//
#include <hip/hip_runtime.h>
#include <math.h>

#define B_ 8
#define T_ 4096
#define M_ 1024
#define CT 8           // outputs per thread along t; 23 = CT+15 independent loads
#define EPSF 1e-6f

typedef float fvec4 __attribute__((ext_vector_type(4)));

// 16-tap causal bump convolution along T + per-channel softplus gate.
// out[b,t,m] = gate[m] * (1/S_t) * sum_{d=0}^{15} w[d] * x[b,t-d,m]
//
// Round-6 post-mortem: launch_bounds(256,2) was a clean NULL (VGPR 68, dur 83
// — scheduler pressure heuristic unchanged). Re-reading ALL rounds exposed the
// real invariant: four structurally unrelated kernels (ring, reg-dbuf,
// spilling, flat tile; occupancy 18-41%; FETCH 65-133 MB) ALL sit at a WRITE
// rate of 1.53-1.67 TB/s, and duration tracks WRITE bytes (r4: +50% writes ->
// +42% dur at constant 1.67 TB/s). The read side was never binding. Common
// factor: __builtin_nontemporal_store — the nt bit streams to HBM bypassing
// L2/L3 and appears to cap at ~1.6 TB/s; store backpressure then stalls wave
// issue (stores count in vmcnt), explaining low VALUBusy across all rounds.
//
// THIS ROUND (single variable vs r6): plain store instead of nt-store.
// Regular stores ride the L2/L3 write-back path (copy ubench: 3.15 TB/s
// write). Risk: out now allocates in L3 and evicts some of x (FETCH may rise
// 65->~130 MB) — acceptable against a 2x write-path win.
__global__ __launch_bounds__(256, 2) void bump_conv_kernel(
    const float* __restrict__ x,
    const float* __restrict__ gate_raw,
    float* __restrict__ out) {
  const int chunks = T_ / CT;              // 512 chunks per batch
  const int nwg = B_ * chunks;             // 4096 blocks
  const int cpx = nwg / 8;                 // 512 per XCD
  const int lin = ((int)blockIdx.x % 8) * cpx + (int)blockIdx.x / 8;
  const int b     = lin / chunks;
  const int chunk = lin % chunks;
  const int t0    = chunk * CT;
  const int m     = threadIdx.x * 4;       // 256 threads * float4 = M_

  // --- taps ---
  float w[16];
  float S = 0.0f;
#pragma unroll
  for (int d = 0; d < 16; ++d) {
    float u = fminf((float)d * (1.0f / 15.0f), 1.0f - EPSF);
    float den = 1.0f - u * u + EPSF;
    w[d] = expf(1.0f - 1.0f / den);        // d=15 -> expf(-3.3e5) == 0.0f
    S += w[d];
  }
  const float rsS = 1.0f / fmaxf(S, EPSF);

  // --- per-channel gate: softplus(gate_raw) ---
  const fvec4 graw = *(const fvec4*)(gate_raw + m);
  fvec4 g;
  g.x = fmaxf(graw.x, 0.0f) + log1pf(expf(-fabsf(graw.x)));
  g.y = fmaxf(graw.y, 0.0f) + log1pf(expf(-fabsf(graw.y)));
  g.z = fmaxf(graw.z, 0.0f) + log1pf(expf(-fabsf(graw.z)));
  g.w = fmaxf(graw.w, 0.0f) + log1pf(expf(-fabsf(graw.w)));

  const float* xb = x   + (size_t)b * T_ * M_ + m;
  float*       ob = out + (size_t)b * T_ * M_ + m;

  // --- 23 independent row loads: rows t0-15 .. t0+7, all static indices ---
  fvec4 v[CT + 15];
#pragma unroll
  for (int j = 0; j < CT + 15; ++j) {
    const int t = t0 - 15 + j;
    v[j] = (t >= 0) ? *(const fvec4*)(xb + (size_t)t * M_)
                    : (fvec4)(0.f);
  }

  // --- 8 outputs; output t=t0+s uses v[s .. s+15] (j = s+15-d) ---
#pragma unroll
  for (int s = 0; s < CT; ++s) {
    const int t = t0 + s;

    float ax = 0.f, ay = 0.f, az = 0.f, aw = 0.f;
#pragma unroll
    for (int d = 0; d < 16; ++d) {
      const fvec4 vv = v[s + 15 - d];      // static index
      const float wd = w[d];
      ax = fmaf(wd, vv.x, ax);
      ay = fmaf(wd, vv.y, ay);
      az = fmaf(wd, vv.z, az);
      aw = fmaf(wd, vv.w, aw);
    }

    float sc = rsS;
    if (t < 15) {                          // only chunks 0,1 of each batch
      float p = 0.0f;
#pragma unroll
      for (int d = 0; d < 16; ++d) p += (d <= t) ? w[d] : 0.0f;
      sc = 1.0f / fmaxf(p, EPSF);
    }

    fvec4 o;
    o.x = ax * sc * g.x;
    o.y = ay * sc * g.y;
    o.z = az * sc * g.z;
    o.w = aw * sc * g.w;
    // PLAIN store (the single variable vs round 6): ride the L2/L3
    // write-back path instead of the nt streaming path.
    *(fvec4*)(ob + (size_t)t * M_) = o;
  }
}

extern "C" void kernel_launch(void* const* d_in, const int* in_sizes, int n_in,
                              void* d_out, int out_size, void* d_ws, size_t ws_size,
                              hipStream_t stream) {
  const float* x         = (const float*)d_in[0];
  // d_in[1] = mask (T,T): redundant (taps already causal) -- intentionally unread.
  const float* gate_raw  = (const float*)d_in[2];
  float*       out       = (float*)d_out;

  dim3 grid(B_ * (T_ / CT));   // 4096 blocks
  dim3 block(256);
  bump_conv_kernel<<<grid, block, 0, stream>>>(x, gate_raw, out);
}

// Round 8
// 258.560 us; speedup vs baseline: 1.1388x; 1.0176x over previous
//
#include <hip/hip_runtime.h>
#include <math.h>

#define B_ 8
#define T_ 4096
#define M_ 1024
#define CT 4           // outputs per thread; 19 = CT+15 rows staged per block
#define NR (CT + 15)   // 19 staged rows
#define EPSF 1e-6f

typedef float fvec4 __attribute__((ext_vector_type(4)));
typedef const void __attribute__((address_space(1)))* gas1_t;
typedef void       __attribute__((address_space(3)))* las3_t;

// 16-tap causal bump convolution along T + per-channel softplus gate.
// out[b,t,m] = gate[m] * (1/S_t) * sum_{d=0}^{15} w[d] * x[b,t-d,m]
//
// Round-7 post-mortem: plain store was WORSE than nt (83->99 us) — nt-store
// ceiling theory refuted, nt restored. What survives all 8 experiments:
// traffic is near-minimal (201 MB ~= floor), the problem is RATE (2.4 vs 6.3
// TB/s), and every register-level MLP attempt was neutered by the compiler's
// pressure heuristic (VGPR pinned 64-84 across 5 structures; 23 live loads
// need >=92). launch_bounds null, sched_barrier spills: the compiler will not
// hold a register load tile.
//
// This version makes MLP STRUCTURAL: global_load_lds DMA has no VGPR
// destination, so nothing can be "sunk" — each wave issues 19 async row
// stages back-to-back (19 KB hardware-queued in flight), drains vmcnt(0)
// once, then computes from LDS. 4 waves/block each own a 1 KB quarter-row
// (LDS dest = wave-uniform base + lane*16, linear — the HW rule), fully
// independent -> ZERO barriers. 76 KB LDS -> 2 blocks/CU, so the co-resident
// block computes while this one drains. Per CU: 8 waves x 19 KB = 152 KB in
// flight >> ~10-30 KB Little's-law need. Halo amplification 4.75x is
// L2-only; swizzle degenerates to XCD x <-> batch x (contiguous 16.7 MB
// stream per XCD).
__global__ __launch_bounds__(256, 2) void bump_conv_kernel(
    const float* __restrict__ x,
    const float* __restrict__ gate_raw,
    float* __restrict__ out) {
  __shared__ float lds[NR * M_];           // 19 rows x 4 KB = 76 KB

  const int chunks = T_ / CT;              // 1024 chunks per batch
  const int nwg = B_ * chunks;             // 8192 blocks
  const int cpx = nwg / 8;                 // 1024 per XCD
  const int lin = ((int)blockIdx.x % 8) * cpx + (int)blockIdx.x / 8;
  const int b     = lin / chunks;          // == blockIdx.x % 8
  const int chunk = lin % chunks;          // == blockIdx.x / 8
  const int t0    = chunk * CT;
  const int tid   = threadIdx.x;
  const int wid   = tid >> 6;              // wave id 0..3 (quarter-row owner)

  // --- taps ---
  float w[16];
  float S = 0.0f;
#pragma unroll
  for (int d = 0; d < 16; ++d) {
    float u = fminf((float)d * (1.0f / 15.0f), 1.0f - EPSF);
    float den = 1.0f - u * u + EPSF;
    w[d] = expf(1.0f - 1.0f / den);        // d=15 -> expf(-3.3e5) == 0.0f
    S += w[d];
  }
  const float rsS = 1.0f / fmaxf(S, EPSF);

  // --- per-channel gate: softplus(gate_raw) ---
  const fvec4 graw = *(const fvec4*)(gate_raw + tid * 4);
  fvec4 g;
  g.x = fmaxf(graw.x, 0.0f) + log1pf(expf(-fabsf(graw.x)));
  g.y = fmaxf(graw.y, 0.0f) + log1pf(expf(-fabsf(graw.y)));
  g.z = fmaxf(graw.z, 0.0f) + log1pf(expf(-fabsf(graw.z)));
  g.w = fmaxf(graw.w, 0.0f) + log1pf(expf(-fabsf(graw.w)));

  // per-lane global column pointer: lane's 16 B of each row
  const float* xb = x   + (size_t)b * T_ * M_ + tid * 4;
  float*       ob = out + (size_t)b * T_ * M_ + tid * 4;

  // --- stage 19 rows via async DMA (no VGPR dest -> nothing to sink) ---
  // LDS layout: row j at bytes [j*4096, j*4096+4096); wave w's quarter at
  // +w*1024; HW writes lane l at base + l*16 — exactly lane's tid*16 slot.
#pragma unroll
  for (int j = 0; j < NR; ++j) {
    const int t = t0 - 15 + j;             // block-uniform -> no divergence
    if (t >= 0) {
      __builtin_amdgcn_global_load_lds(
          (gas1_t)(const void*)(xb + (size_t)t * M_),
          (las3_t)(void*)&lds[j * M_ + wid * 256],   // wave-uniform base
          16, 0, 0);
    } else {
      *(fvec4*)&lds[j * M_ + tid * 4] = (fvec4)(0.f);  // zero halo row
    }
  }
  // Drain the DMA queue once (per-wave; no barrier needed — each wave only
  // reads its own staged quarter). "memory" clobber orders the ds_reads.
  asm volatile("s_waitcnt vmcnt(0)" ::: "memory");

  // --- read staged rows (LDS latency ~120 cy, cheap; conflict-free b128) ---
  fvec4 v[NR];
#pragma unroll
  for (int j = 0; j < NR; ++j)
    v[j] = *(const fvec4*)&lds[j * M_ + tid * 4];

  // --- 4 outputs; output t=t0+s uses v[s .. s+15] (j = s+15-d) ---
#pragma unroll
  for (int s = 0; s < CT; ++s) {
    const int t = t0 + s;

    float ax = 0.f, ay = 0.f, az = 0.f, aw = 0.f;
#pragma unroll
    for (int d = 0; d < 16; ++d) {
      const fvec4 vv = v[s + 15 - d];      // static index
      const float wd = w[d];
      ax = fmaf(wd, vv.x, ax);
      ay = fmaf(wd, vv.y, ay);
      az = fmaf(wd, vv.z, az);
      aw = fmaf(wd, vv.w, aw);
    }

    float sc = rsS;
    if (t < 15) {                          // only the first 4 chunks of each b
      float p = 0.0f;
#pragma unroll
      for (int d = 0; d < 16; ++d) p += (d <= t) ? w[d] : 0.0f;
      sc = 1.0f / fmaxf(p, EPSF);
    }

    fvec4 o;
    o.x = ax * sc * g.x;
    o.y = ay * sc * g.y;
    o.z = az * sc * g.z;
    o.w = aw * sc * g.w;
    // nt-store: r6 vs r7 A/B showed nt beats plain by 19% here.
    __builtin_nontemporal_store(o, (fvec4*)(ob + (size_t)t * M_));
  }
}

extern "C" void kernel_launch(void* const* d_in, const int* in_sizes, int n_in,
                              void* d_out, int out_size, void* d_ws, size_t ws_size,
                              hipStream_t stream) {
  const float* x         = (const float*)d_in[0];
  // d_in[1] = mask (T,T): redundant (taps already causal) -- intentionally unread.
  const float* gate_raw  = (const float*)d_in[2];
  float*       out       = (float*)d_out;

  dim3 grid(B_ * (T_ / CT));   // 8192 blocks
  dim3 block(256);
  bump_conv_kernel<<<grid, block, 0, stream>>>(x, gate_raw, out);
}